// Round 1
// baseline (269.539 us; speedup 1.0000x reference)
//
#include <hip/hip_runtime.h>

#define VOCAB_SZ 50257
#define DIM 1024
#define BLANK_ID 100
#define BATCH 4
#define SEQ 4096

// One block per (b, s) row. 256 threads x float4 = 1024 floats = one D row.
// out[b,s] = emb[x[s]] + c1*emb[x[s-1]] + c2*emb[x[s-2]] + c3*emb[x[s-3]]
//   c1 = s>=1 && x[s]  ==BLANK && x[s-1]!=BLANK   (pos s-1 is preblank, shifted 1)
//   c2 = s>=2 && x[s-1]==BLANK && x[s-2]!=BLANK   (pos s-2 is preblank, shifted 2)
//   c3 = s>=3 && x[s-2]==BLANK && x[s-3]!=BLANK   (pos s-3 is preblank, shifted 3)
__global__ __launch_bounds__(256) void BlankEmbedding_kernel(
    const int* __restrict__ x, const float* __restrict__ emb,
    float* __restrict__ out) {
  const int r = blockIdx.x;        // flat row in [0, B*S)
  const int s = r & (SEQ - 1);     // seq position

  // Block-uniform token loads (guarded at batch boundaries).
  const int t0  = x[r];
  const int tm1 = (s >= 1) ? x[r - 1] : -1;
  const int tm2 = (s >= 2) ? x[r - 2] : -1;
  const int tm3 = (s >= 3) ? x[r - 3] : -1;

  const bool c1 = (s >= 1) && (t0  == BLANK_ID) && (tm1 != BLANK_ID);
  const bool c2 = (s >= 2) && (tm1 == BLANK_ID) && (tm2 != BLANK_ID);
  const bool c3 = (s >= 3) && (tm2 == BLANK_ID) && (tm3 != BLANK_ID);

  const int d = threadIdx.x << 2;  // float offset within the row

  float4 acc = *(const float4*)(emb + (size_t)t0 * DIM + d);
  if (c1) {
    float4 v = *(const float4*)(emb + (size_t)tm1 * DIM + d);
    acc.x += v.x; acc.y += v.y; acc.z += v.z; acc.w += v.w;
  }
  if (c2) {
    float4 v = *(const float4*)(emb + (size_t)tm2 * DIM + d);
    acc.x += v.x; acc.y += v.y; acc.z += v.z; acc.w += v.w;
  }
  if (c3) {
    float4 v = *(const float4*)(emb + (size_t)tm3 * DIM + d);
    acc.x += v.x; acc.y += v.y; acc.z += v.z; acc.w += v.w;
  }

  *(float4*)(out + (size_t)r * DIM + d) = acc;
}

extern "C" void kernel_launch(void* const* d_in, const int* in_sizes, int n_in,
                              void* d_out, int out_size, void* d_ws, size_t ws_size,
                              hipStream_t stream) {
  const int*   x   = (const int*)d_in[0];     // [B, S] tokens (int32)
  const float* emb = (const float*)d_in[1];   // [VOCAB, DIM] fp32
  float*       out = (float*)d_out;           // [B, S, DIM] fp32

  dim3 grid(BATCH * SEQ);
  dim3 block(256);
  BlankEmbedding_kernel<<<grid, block, 0, stream>>>(x, emb, out);
}